// Round 1
// baseline (1640.132 us; speedup 1.0000x reference)
//
#include <hip/hip_runtime.h>

#define NTOK 2048      // B*T
#define DMODEL 1024
#define NHEADS 16
#define HD_ 64
#define TSEQ 1024
#define DFF_ 4096
#define NVOCAB 16384

typedef unsigned short u16;
typedef unsigned int u32;
typedef __bf16 bf16x8 __attribute__((ext_vector_type(8)));
typedef float floatx4 __attribute__((ext_vector_type(4)));

__device__ __forceinline__ u16 f2bf(float f) {
  u32 u = __float_as_uint(f);
  u += 0x7FFFu + ((u >> 16) & 1u);   // RNE
  return (u16)(u >> 16);
}
__device__ __forceinline__ float bf2f(u16 h) {
  return __uint_as_float(((u32)h) << 16);
}

// async global->LDS, 16B per lane. LDS dest is wave-uniform base + lane*16
// (our slot index is tid-linear so this holds); global src is per-lane arbitrary.
__device__ __forceinline__ void gload_lds16(const void* g, void* l) {
  __builtin_amdgcn_global_load_lds(
      (const __attribute__((address_space(1))) void*)g,
      (__attribute__((address_space(3))) void*)l, 16, 0, 0);
}

// ---------------- converts ----------------
__global__ void convert_bf16(const float* __restrict__ src, u16* __restrict__ dst, int n4) {
  int i = blockIdx.x * blockDim.x + threadIdx.x;
  int stride = gridDim.x * blockDim.x;
  for (; i < n4; i += stride) {
    float4 v = ((const float4*)src)[i];
    ushort4 o;
    o.x = f2bf(v.x); o.y = f2bf(v.y); o.z = f2bf(v.z); o.w = f2bf(v.w);
    ((ushort4*)dst)[i] = o;
  }
}

// one launch per layer: wq,wk,wv -> wqkv ; wo -> wo_b ; w1,w3 -> w13 ; w2 -> w2_b
__global__ void convert_layer(const float* __restrict__ wq, const float* __restrict__ wk,
                              const float* __restrict__ wv, const float* __restrict__ wo,
                              const float* __restrict__ w1, const float* __restrict__ w3,
                              const float* __restrict__ w2,
                              u16* __restrict__ wqkv, u16* __restrict__ wo_b,
                              u16* __restrict__ w13, u16* __restrict__ w2_b) {
  int i = blockIdx.x * blockDim.x + threadIdx.x;  // float4 units, 16M elems total
  int stride = gridDim.x * blockDim.x;
  for (; i < 4194304; i += stride) {
    const float* s; u16* d; int j;
    if (i < 262144)       { s = wq; d = wqkv;           j = i; }
    else if (i < 524288)  { s = wk; d = wqkv + 1048576; j = i - 262144; }
    else if (i < 786432)  { s = wv; d = wqkv + 2097152; j = i - 524288; }
    else if (i < 1048576) { s = wo; d = wo_b;           j = i - 786432; }
    else if (i < 2097152) { s = w1; d = w13;            j = i - 1048576; }
    else if (i < 3145728) { s = w3; d = w13 + 4194304;  j = i - 2097152; }
    else                  { s = w2; d = w2_b;           j = i - 3145728; }
    float4 v = ((const float4*)s)[j];
    ushort4 o;
    o.x = f2bf(v.x); o.y = f2bf(v.y); o.z = f2bf(v.z); o.w = f2bf(v.w);
    ((ushort4*)d)[j] = o;
  }
}

// ---------------- embedding gather (fp32) ----------------
__global__ void gather_embed(const int* __restrict__ tok, const float* __restrict__ embed,
                             float* __restrict__ x) {
  int m = blockIdx.x;
  int t = tok[m];
  float4 v = ((const float4*)(embed + (long)t * DMODEL))[threadIdx.x];
  ((float4*)(x + (long)m * DMODEL))[threadIdx.x] = v;
}

// ---------------- rmsnorm: fp32 in -> bf16 out ----------------
__global__ void rmsnorm_bf16(const float* __restrict__ x, const float* __restrict__ w,
                             u16* __restrict__ out) {
  __shared__ float red[9];
  int m = blockIdx.x;
  int tid = threadIdx.x, lane = tid & 63, wave = tid >> 6;
  float4 v = ((const float4*)(x + (long)m * DMODEL))[tid];
  float ss = v.x * v.x + v.y * v.y + v.z * v.z + v.w * v.w;
  for (int o2 = 32; o2 > 0; o2 >>= 1) ss += __shfl_down(ss, o2);
  if (lane == 0) red[wave] = ss;
  __syncthreads();
  if (tid == 0) red[8] = rsqrtf((red[0] + red[1] + red[2] + red[3]) * (1.0f / 1024.0f) + 1e-6f);
  __syncthreads();
  float inv = red[8];
  float4 wv = ((const float4*)w)[tid];
  ushort4 o;
  o.x = f2bf(v.x * inv * wv.x); o.y = f2bf(v.y * inv * wv.y);
  o.z = f2bf(v.z * inv * wv.z); o.w = f2bf(v.w * inv * wv.w);
  ((ushort4*)(out + (long)m * DMODEL))[tid] = o;
}

// ---------------- RoPE on q,k inside qkv[2048][3072] (bf16, in place) ----------------
__global__ void rope_qk(u16* __restrict__ qkv, const int* __restrict__ pos_ids) {
  __shared__ float cs[32], sn[32];
  int m = blockIdx.x;                 // b*T + t
  int tid = threadIdx.x;
  if (tid < 32) {
    // inv_freq = 10000^(-2i/64) = exp(-i * ln(10000)/32)
    float inv = expf(-(float)tid * (9.210340371976184f / 32.0f));
    float ang = (float)pos_ids[m] * inv;
    float s, c;
    sincosf(ang, &s, &c);
    cs[tid] = c; sn[tid] = s;
  }
  __syncthreads();
  u16* row = qkv + (long)m * 3072;
  for (int part = 0; part < 2; part++) {      // q then k
    u16* base = row + part * 1024;
    for (int pp = tid; pp < 512; pp += 256) { // pair index: h*32 + i
      int i = pp & 31;
      u32* p = (u32*)(base + pp * 2);
      u32 v = *p;
      float xr = bf2f((u16)(v & 0xFFFF));
      float xi = bf2f((u16)(v >> 16));
      float c = cs[i], s = sn[i];
      float orr = xr * c - xi * s;
      float oii = xr * s + xi * c;
      *p = (u32)f2bf(orr) | ((u32)f2bf(oii) << 16);
    }
  }
}

// ---------------- transpose V slice of qkv -> vT[b,h,d,t] ----------------
__global__ void transpose_v(const u16* __restrict__ qkv, u16* __restrict__ vT) {
  __shared__ u16 tile[64][65];
  int tb = blockIdx.x;   // t block (0..15)
  int bh = blockIdx.y;   // b*16+h (0..31)
  int b = bh >> 4, h = bh & 15;
  const u16* src = qkv + ((long)(b * TSEQ + tb * 64)) * 3072 + 2048 + h * 64;
  for (int i = 0; i < 16; i++) {
    int e = threadIdx.x + i * 256;
    int t = e >> 6, d = e & 63;
    tile[t][d] = src[(long)t * 3072 + d];
  }
  __syncthreads();
  u16* dst = vT + ((long)bh * 64) * TSEQ + tb * 64;
  for (int i = 0; i < 16; i++) {
    int e = threadIdx.x + i * 256;
    int d = e >> 6, t = e & 63;
    dst[(long)d * TSEQ + t] = tile[t][d];
  }
}

// ---------------- row softmax on bf16 S (in place), row = 1024 ----------------
__global__ void softmax_rows(u16* __restrict__ S) {
  __shared__ float red[9];
  long row = blockIdx.x;
  u16* p = S + row * 1024;
  int tid = threadIdx.x, lane = tid & 63, wave = tid >> 6;
  ushort4 v4 = ((const ushort4*)p)[tid];
  float v0 = bf2f(v4.x), v1 = bf2f(v4.y), v2 = bf2f(v4.z), v3 = bf2f(v4.w);
  float mx = fmaxf(fmaxf(v0, v1), fmaxf(v2, v3));
  for (int o2 = 32; o2 > 0; o2 >>= 1) mx = fmaxf(mx, __shfl_down(mx, o2));
  if (lane == 0) red[wave] = mx;
  __syncthreads();
  if (tid == 0) red[8] = fmaxf(fmaxf(red[0], red[1]), fmaxf(red[2], red[3]));
  __syncthreads();
  mx = red[8];
  float e0 = __expf(v0 - mx), e1 = __expf(v1 - mx), e2 = __expf(v2 - mx), e3 = __expf(v3 - mx);
  float s = e0 + e1 + e2 + e3;
  for (int o2 = 32; o2 > 0; o2 >>= 1) s += __shfl_down(s, o2);
  if (lane == 0) red[wave] = s;
  __syncthreads();
  if (tid == 0) red[8] = red[0] + red[1] + red[2] + red[3];
  __syncthreads();
  float inv = 1.0f / red[8];
  ushort4 o;
  o.x = f2bf(e0 * inv); o.y = f2bf(e1 * inv); o.z = f2bf(e2 * inv); o.w = f2bf(e3 * inv);
  ((ushort4*)p)[tid] = o;
}

// ---------------- swiglu (x8 vectorized): g = silu(t13[:, :4096]) * t13[:, 4096:] ----------------
__global__ void swiglu(const u16* __restrict__ t13, u16* __restrict__ g) {
  int i = blockIdx.x * 256 + threadIdx.x;     // 8-elem groups, 2048*4096/8 = 1M
  int m = i >> 9, f8 = i & 511;
  const ushort4* pa = (const ushort4*)(t13 + (long)m * 8192 + f8 * 8);
  const ushort4* pb = (const ushort4*)(t13 + (long)m * 8192 + 4096 + f8 * 8);
  ushort4 a0 = pa[0], a1 = pa[1];
  ushort4 b0 = pb[0], b1 = pb[1];
  ushort4 o0, o1;
  float a, b;
#define SWG(av, bv, ov) \
  a = bf2f(av); b = bf2f(bv); ov = f2bf(a * b / (1.0f + __expf(-a)));
  SWG(a0.x, b0.x, o0.x) SWG(a0.y, b0.y, o0.y) SWG(a0.z, b0.z, o0.z) SWG(a0.w, b0.w, o0.w)
  SWG(a1.x, b1.x, o1.x) SWG(a1.y, b1.y, o1.y) SWG(a1.z, b1.z, o1.z) SWG(a1.w, b1.w, o1.w)
#undef SWG
  ushort4* po = (ushort4*)(g + (long)m * 4096 + f8 * 8);
  po[0] = o0; po[1] = o1;
}

// ---------------- bf16 NT GEMM: C[M,N] = A[M,K] * B[N,K]^T ----------------
// global_load_lds (16B) staging, XOR-swizzled via the GLOBAL source address
// (LDS slot = tid-linear as required by the wave-uniform-base semantics).
// mode 0: store fp32; mode 1: store bf16 (scaled); mode 2: fp32 +=
// batch via blockIdx.z: zb=z>>4, zh=z&15; base += zb*sb + zh*sh
template <int BM, int BN, int WR, int WC>
__global__ __launch_bounds__(WR * WC * 64) void gemm_nt(
    const u16* __restrict__ A, int lda, long a_sb, long a_sh,
    const u16* __restrict__ B, int ldb, long b_sb, long b_sh,
    void* __restrict__ C, int ldc, long c_sb, long c_sh,
    int K, float scale, int mode) {
  constexpr int NW = WR * WC;
  constexpr int NTHR = NW * 64;
  constexpr int WTM = BM / WR;
  constexpr int WTN = BN / WC;
  constexpr int MT = WTM / 16;
  constexpr int NT = WTN / 16;
  constexpr int ISA = (BM * 64) / (NTHR * 16);  // 16B slots per thread for A tile
  constexpr int ISB = (BN * 64) / (NTHR * 16);
  static_assert(ISA >= 1 && ISB >= 1, "tile too small");

  __shared__ __align__(16) u16 lA[BM * 32];
  __shared__ __align__(16) u16 lB[BN * 32];

  const int tid = threadIdx.x;
  const int lane = tid & 63;
  const int wave = tid >> 6;
  const int wm = wave / WC;
  const int wn = wave % WC;
  const int m0 = blockIdx.y * BM;
  const int n0 = blockIdx.x * BN;
  const int zb = blockIdx.z >> 4;
  const int zh = blockIdx.z & 15;
  A += (long)zb * a_sb + (long)zh * a_sh;
  B += (long)zb * b_sb + (long)zh * b_sh;
  const long c0 = (long)zb * c_sb + (long)zh * c_sh;

  floatx4 acc[MT][NT];
  for (int mi = 0; mi < MT; mi++)
    for (int ni = 0; ni < NT; ni++)
      for (int r = 0; r < 4; r++) acc[mi][ni][r] = 0.0f;

  const int q_ = lane >> 4;  // 16B chunk wanted by this lane's fragment reads

  for (int k0 = 0; k0 < K; k0 += 32) {
    // stage tiles [BM][32] via async global->LDS; LDS[r][c] = G[r][c ^ ((r>>1)&3)]
    const u16* Ag = A + (long)m0 * lda + k0;
#pragma unroll
    for (int i = 0; i < ISA; i++) {
      int e = (tid + i * NTHR) * 8;   // element offset of this 16B slot (tid-linear)
      int r = e >> 5;
      int c = (e >> 3) & 3;
      int csw = c ^ ((r >> 1) & 3);
      gload_lds16(Ag + (long)r * lda + (csw << 3), &lA[e]);
    }
    const u16* Bg = B + (long)n0 * ldb + k0;
#pragma unroll
    for (int i = 0; i < ISB; i++) {
      int e = (tid + i * NTHR) * 8;
      int r = e >> 5;
      int c = (e >> 3) & 3;
      int csw = c ^ ((r >> 1) & 3);
      gload_lds16(Bg + (long)r * ldb + (csw << 3), &lB[e]);
    }
    __syncthreads();

    bf16x8 af[MT], bfr[NT];
#pragma unroll
    for (int mi = 0; mi < MT; mi++) {
      int r = wm * WTM + mi * 16 + (lane & 15);
      af[mi] = *(const bf16x8*)&lA[(r << 5) + ((q_ ^ ((r >> 1) & 3)) << 3)];
    }
#pragma unroll
    for (int ni = 0; ni < NT; ni++) {
      int r = wn * WTN + ni * 16 + (lane & 15);
      bfr[ni] = *(const bf16x8*)&lB[(r << 5) + ((q_ ^ ((r >> 1) & 3)) << 3)];
    }
#pragma unroll
    for (int mi = 0; mi < MT; mi++)
#pragma unroll
      for (int ni = 0; ni < NT; ni++)
        acc[mi][ni] = __builtin_amdgcn_mfma_f32_16x16x32_bf16(af[mi], bfr[ni], acc[mi][ni], 0, 0, 0);
    __syncthreads();
  }

  // epilogue: D col = lane&15, row = (lane>>4)*4 + reg  [verified m89/m91]
#pragma unroll
  for (int mi = 0; mi < MT; mi++) {
#pragma unroll
    for (int ni = 0; ni < NT; ni++) {
      int col = n0 + wn * WTN + ni * 16 + (lane & 15);
      int rbase = m0 + wm * WTM + mi * 16 + (lane >> 4) * 4;
#pragma unroll
      for (int r = 0; r < 4; r++) {
        float v = acc[mi][ni][r] * scale;
        long idx = c0 + (long)(rbase + r) * ldc + col;
        if (mode == 0)       ((float*)C)[idx] = v;
        else if (mode == 1)  ((u16*)C)[idx] = f2bf(v);
        else                 ((float*)C)[idx] += v;
      }
    }
  }
}

extern "C" void kernel_launch(void* const* d_in, const int* in_sizes, int n_in,
                              void* d_out, int out_size, void* d_ws, size_t ws_size,
                              hipStream_t stream) {
  const int*   tok         = (const int*)d_in[0];
  const int*   pos         = (const int*)d_in[1];
  const float* embed       = (const float*)d_in[2];
  const float* attn_norm_w = (const float*)d_in[3];
  const float* wq          = (const float*)d_in[4];
  const float* wk          = (const float*)d_in[5];
  const float* wv          = (const float*)d_in[6];
  const float* wo          = (const float*)d_in[7];
  const float* ff_norm_w   = (const float*)d_in[8];
  const float* w1          = (const float*)d_in[9];
  const float* w2          = (const float*)d_in[10];
  const float* w3          = (const float*)d_in[11];
  const float* norm_w      = (const float*)d_in[12];

  char* ws = (char*)d_ws;
  u16*   ebf  = (u16*)(ws);                      // 33,554,432 B  (embed bf16)
  u16*   wqkv = (u16*)(ws + 33554432);           //  6,291,456 B
  u16*   wo_b = (u16*)(ws + 39845888);           //  2,097,152 B
  u16*   w13  = (u16*)(ws + 41943040);           // 16,777,216 B
  u16*   w2_b = (u16*)(ws + 58720256);           //  8,388,608 B
  float* x    = (float*)(ws + 67108864);         //  8,388,608 B  (residual, fp32)
  u16*   h    = (u16*)(ws + 75497472);           //  4,194,304 B  (normed, bf16)
  u16*   qkv  = (u16*)(ws + 79691776);           // 12,582,912 B
  u16*   vT   = (u16*)(ws + 92274688);           //  4,194,304 B  [b,h,d,t]
  u16*   o    = (u16*)(ws + 96468992);           //  4,194,304 B
  u16*   S    = (u16*)(ws + 100663296);          // 67,108,864 B  (scores/probs)
  u16*   t13  = S;                               // aliases S (not concurrent)
  u16*   g    = (u16*)(ws + 134217728);          //  8,388,608 B  (aliases S tail)
  // total footprint: 160 MB

  convert_bf16<<<16384, 256, 0, stream>>>(embed, ebf, NVOCAB * DMODEL / 4);
  gather_embed<<<NTOK, 256, 0, stream>>>(tok, embed, x);

  for (int l = 0; l < 4; l++) {
    convert_layer<<<16384, 256, 0, stream>>>(
        wq + (long)l * 1048576, wk + (long)l * 1048576, wv + (long)l * 1048576,
        wo + (long)l * 1048576, w1 + (long)l * 4194304, w3 + (long)l * 4194304,
        w2 + (long)l * 4194304, wqkv, wo_b, w13, w2_b);

    // attention
    rmsnorm_bf16<<<NTOK, 256, 0, stream>>>(x, attn_norm_w + l * 1024, h);
    gemm_nt<128, 128, 2, 2><<<dim3(24, 16, 1), 256, 0, stream>>>(
        h, 1024, 0, 0, wqkv, 1024, 0, 0, qkv, 3072, 0, 0, 1024, 1.0f, 1);
    rope_qk<<<NTOK, 256, 0, stream>>>(qkv, pos);
    transpose_v<<<dim3(16, 32), 256, 0, stream>>>(qkv, vT);
    // S[z][t][s] = (q . k) * 1/8,  z = b*16+h
    gemm_nt<128, 128, 2, 2><<<dim3(8, 8, 32), 256, 0, stream>>>(
        qkv, 3072, 3145728L, 64L,
        qkv + 1024, 3072, 3145728L, 64L,
        S, 1024, 16777216L, 1048576L, 64, 0.125f, 1);
    softmax_rows<<<32768, 256, 0, stream>>>(S);
    // O[z][t][d] = P . vT   (64x64 tile -> 512 blocks = 2/CU; was 256 = 1/CU)
    gemm_nt<64, 64, 2, 2><<<dim3(1, 16, 32), 256, 0, stream>>>(
        S, 1024, 16777216L, 1048576L,
        vT, 1024, 1048576L, 65536L,
        o, 1024, 1048576L, 64L, 1024, 1.0f, 1);
    // x += O @ wo^T
    gemm_nt<64, 128, 2, 2><<<dim3(8, 32, 1), 256, 0, stream>>>(
        o, 1024, 0, 0, wo_b, 1024, 0, 0, x, 1024, 0, 0, 1024, 1.0f, 2);

    // FFN
    rmsnorm_bf16<<<NTOK, 256, 0, stream>>>(x, ff_norm_w + l * 1024, h);
    gemm_nt<128, 128, 2, 2><<<dim3(64, 16, 1), 256, 0, stream>>>(
        h, 1024, 0, 0, w13, 1024, 0, 0, t13, 8192, 0, 0, 1024, 1.0f, 1);
    swiglu<<<4096, 256, 0, stream>>>(t13, g);
    gemm_nt<64, 128, 2, 2><<<dim3(8, 32, 1), 256, 0, stream>>>(
        g, 4096, 0, 0, w2_b, 4096, 0, 0, x, 1024, 0, 0, 4096, 1.0f, 2);
  }

  rmsnorm_bf16<<<NTOK, 256, 0, stream>>>(x, norm_w, h);
  // logits = xn @ embed^T  -> d_out fp32 [2048, 16384]
  gemm_nt<128, 128, 2, 2><<<dim3(128, 16, 1), 256, 0, stream>>>(
      h, 1024, 0, 0, ebf, 1024, 0, 0, d_out, 16384, 0, 0, 1024, 1.0f, 0);
}

// Round 2
// 1522.755 us; speedup vs baseline: 1.0771x; 1.0771x over previous
//
#include <hip/hip_runtime.h>

#define NTOK 2048      // B*T
#define DMODEL 1024
#define NHEADS 16
#define HD_ 64
#define TSEQ 1024
#define DFF_ 4096
#define NVOCAB 16384

typedef unsigned short u16;
typedef unsigned int u32;
typedef __bf16 bf16x8 __attribute__((ext_vector_type(8)));
typedef float floatx4 __attribute__((ext_vector_type(4)));

__device__ __forceinline__ u16 f2bf(float f) {
  u32 u = __float_as_uint(f);
  u += 0x7FFFu + ((u >> 16) & 1u);   // RNE
  return (u16)(u >> 16);
}
__device__ __forceinline__ float bf2f(u16 h) {
  return __uint_as_float(((u32)h) << 16);
}

// async global->LDS, 16B per lane. LDS dest is wave-uniform base + lane*16
// (our slot index is tid-linear so this holds); global src is per-lane arbitrary.
__device__ __forceinline__ void gload_lds16(const void* g, void* l) {
  __builtin_amdgcn_global_load_lds(
      (const __attribute__((address_space(1))) void*)g,
      (__attribute__((address_space(3))) void*)l, 16, 0, 0);
}

// ---------------- converts ----------------
__global__ void convert_bf16(const float* __restrict__ src, u16* __restrict__ dst, int n4) {
  int i = blockIdx.x * blockDim.x + threadIdx.x;
  int stride = gridDim.x * blockDim.x;
  for (; i < n4; i += stride) {
    float4 v = ((const float4*)src)[i];
    ushort4 o;
    o.x = f2bf(v.x); o.y = f2bf(v.y); o.z = f2bf(v.z); o.w = f2bf(v.w);
    ((ushort4*)dst)[i] = o;
  }
}

// one launch per layer: wq,wk,wv -> wqkv ; wo -> wo_b ; w1,w3 -> w13 ; w2 -> w2_b
__global__ void convert_layer(const float* __restrict__ wq, const float* __restrict__ wk,
                              const float* __restrict__ wv, const float* __restrict__ wo,
                              const float* __restrict__ w1, const float* __restrict__ w3,
                              const float* __restrict__ w2,
                              u16* __restrict__ wqkv, u16* __restrict__ wo_b,
                              u16* __restrict__ w13, u16* __restrict__ w2_b) {
  int i = blockIdx.x * blockDim.x + threadIdx.x;  // float4 units, 16M elems total
  int stride = gridDim.x * blockDim.x;
  for (; i < 4194304; i += stride) {
    const float* s; u16* d; int j;
    if (i < 262144)       { s = wq; d = wqkv;           j = i; }
    else if (i < 524288)  { s = wk; d = wqkv + 1048576; j = i - 262144; }
    else if (i < 786432)  { s = wv; d = wqkv + 2097152; j = i - 524288; }
    else if (i < 1048576) { s = wo; d = wo_b;           j = i - 786432; }
    else if (i < 2097152) { s = w1; d = w13;            j = i - 1048576; }
    else if (i < 3145728) { s = w3; d = w13 + 4194304;  j = i - 2097152; }
    else                  { s = w2; d = w2_b;           j = i - 3145728; }
    float4 v = ((const float4*)s)[j];
    ushort4 o;
    o.x = f2bf(v.x); o.y = f2bf(v.y); o.z = f2bf(v.z); o.w = f2bf(v.w);
    ((ushort4*)d)[j] = o;
  }
}

// ---------------- embedding gather (fp32) ----------------
__global__ void gather_embed(const int* __restrict__ tok, const float* __restrict__ embed,
                             float* __restrict__ x) {
  int m = blockIdx.x;
  int t = tok[m];
  float4 v = ((const float4*)(embed + (long)t * DMODEL))[threadIdx.x];
  ((float4*)(x + (long)m * DMODEL))[threadIdx.x] = v;
}

// ---------------- rmsnorm: fp32 in -> bf16 out ----------------
__global__ void rmsnorm_bf16(const float* __restrict__ x, const float* __restrict__ w,
                             u16* __restrict__ out) {
  __shared__ float red[9];
  int m = blockIdx.x;
  int tid = threadIdx.x, lane = tid & 63, wave = tid >> 6;
  float4 v = ((const float4*)(x + (long)m * DMODEL))[tid];
  float ss = v.x * v.x + v.y * v.y + v.z * v.z + v.w * v.w;
  for (int o2 = 32; o2 > 0; o2 >>= 1) ss += __shfl_down(ss, o2);
  if (lane == 0) red[wave] = ss;
  __syncthreads();
  if (tid == 0) red[8] = rsqrtf((red[0] + red[1] + red[2] + red[3]) * (1.0f / 1024.0f) + 1e-6f);
  __syncthreads();
  float inv = red[8];
  float4 wv = ((const float4*)w)[tid];
  ushort4 o;
  o.x = f2bf(v.x * inv * wv.x); o.y = f2bf(v.y * inv * wv.y);
  o.z = f2bf(v.z * inv * wv.z); o.w = f2bf(v.w * inv * wv.w);
  ((ushort4*)(out + (long)m * DMODEL))[tid] = o;
}

// ---------------- RoPE on q,k inside qkv[2048][3072] (bf16, in place) ----------------
__global__ void rope_qk(u16* __restrict__ qkv, const int* __restrict__ pos_ids) {
  __shared__ float cs[32], sn[32];
  int m = blockIdx.x;                 // b*T + t
  int tid = threadIdx.x;
  if (tid < 32) {
    // inv_freq = 10000^(-2i/64) = exp(-i * ln(10000)/32)
    float inv = expf(-(float)tid * (9.210340371976184f / 32.0f));
    float ang = (float)pos_ids[m] * inv;
    float s, c;
    sincosf(ang, &s, &c);
    cs[tid] = c; sn[tid] = s;
  }
  __syncthreads();
  u16* row = qkv + (long)m * 3072;
  for (int part = 0; part < 2; part++) {      // q then k
    u16* base = row + part * 1024;
    for (int pp = tid; pp < 512; pp += 256) { // pair index: h*32 + i
      int i = pp & 31;
      u32* p = (u32*)(base + pp * 2);
      u32 v = *p;
      float xr = bf2f((u16)(v & 0xFFFF));
      float xi = bf2f((u16)(v >> 16));
      float c = cs[i], s = sn[i];
      float orr = xr * c - xi * s;
      float oii = xr * s + xi * c;
      *p = (u32)f2bf(orr) | ((u32)f2bf(oii) << 16);
    }
  }
}

// ---------------- transpose V slice of qkv -> vT[b,h,d,t] ----------------
__global__ void transpose_v(const u16* __restrict__ qkv, u16* __restrict__ vT) {
  __shared__ u16 tile[64][65];
  int tb = blockIdx.x;   // t block (0..15)
  int bh = blockIdx.y;   // b*16+h (0..31)
  int b = bh >> 4, h = bh & 15;
  const u16* src = qkv + ((long)(b * TSEQ + tb * 64)) * 3072 + 2048 + h * 64;
  for (int i = 0; i < 16; i++) {
    int e = threadIdx.x + i * 256;
    int t = e >> 6, d = e & 63;
    tile[t][d] = src[(long)t * 3072 + d];
  }
  __syncthreads();
  u16* dst = vT + ((long)bh * 64) * TSEQ + tb * 64;
  for (int i = 0; i < 16; i++) {
    int e = threadIdx.x + i * 256;
    int d = e >> 6, t = e & 63;
    dst[(long)d * TSEQ + t] = tile[t][d];
  }
}

// ---------------- row softmax on bf16 S (in place), row = 1024 ----------------
__global__ void softmax_rows(u16* __restrict__ S) {
  __shared__ float red[9];
  long row = blockIdx.x;
  u16* p = S + row * 1024;
  int tid = threadIdx.x, lane = tid & 63, wave = tid >> 6;
  ushort4 v4 = ((const ushort4*)p)[tid];
  float v0 = bf2f(v4.x), v1 = bf2f(v4.y), v2 = bf2f(v4.z), v3 = bf2f(v4.w);
  float mx = fmaxf(fmaxf(v0, v1), fmaxf(v2, v3));
  for (int o2 = 32; o2 > 0; o2 >>= 1) mx = fmaxf(mx, __shfl_down(mx, o2));
  if (lane == 0) red[wave] = mx;
  __syncthreads();
  if (tid == 0) red[8] = fmaxf(fmaxf(red[0], red[1]), fmaxf(red[2], red[3]));
  __syncthreads();
  mx = red[8];
  float e0 = __expf(v0 - mx), e1 = __expf(v1 - mx), e2 = __expf(v2 - mx), e3 = __expf(v3 - mx);
  float s = e0 + e1 + e2 + e3;
  for (int o2 = 32; o2 > 0; o2 >>= 1) s += __shfl_down(s, o2);
  if (lane == 0) red[wave] = s;
  __syncthreads();
  if (tid == 0) red[8] = red[0] + red[1] + red[2] + red[3];
  __syncthreads();
  float inv = 1.0f / red[8];
  ushort4 o;
  o.x = f2bf(e0 * inv); o.y = f2bf(e1 * inv); o.z = f2bf(e2 * inv); o.w = f2bf(e3 * inv);
  ((ushort4*)p)[tid] = o;
}

// ---------------- swiglu (x8 vectorized): g = silu(t13[:, :4096]) * t13[:, 4096:] ----------------
__global__ void swiglu(const u16* __restrict__ t13, u16* __restrict__ g) {
  int i = blockIdx.x * 256 + threadIdx.x;     // 8-elem groups, 2048*4096/8 = 1M
  int m = i >> 9, f8 = i & 511;
  const ushort4* pa = (const ushort4*)(t13 + (long)m * 8192 + f8 * 8);
  const ushort4* pb = (const ushort4*)(t13 + (long)m * 8192 + 4096 + f8 * 8);
  ushort4 a0 = pa[0], a1 = pa[1];
  ushort4 b0 = pb[0], b1 = pb[1];
  ushort4 o0, o1;
  float a, b;
#define SWG(av, bv, ov) \
  a = bf2f(av); b = bf2f(bv); ov = f2bf(a * b / (1.0f + __expf(-a)));
  SWG(a0.x, b0.x, o0.x) SWG(a0.y, b0.y, o0.y) SWG(a0.z, b0.z, o0.z) SWG(a0.w, b0.w, o0.w)
  SWG(a1.x, b1.x, o1.x) SWG(a1.y, b1.y, o1.y) SWG(a1.z, b1.z, o1.z) SWG(a1.w, b1.w, o1.w)
#undef SWG
  ushort4* po = (ushort4*)(g + (long)m * 4096 + f8 * 8);
  po[0] = o0; po[1] = o1;
}

// ---------------- bf16 NT GEMM: C[M,N] = A[M,K] * B[N,K]^T ----------------
// global_load_lds (16B) staging, XOR-swizzled via the GLOBAL source address
// (LDS slot = tid-linear as required by the wave-uniform-base semantics).
// mode 0: store fp32; mode 1: store bf16 (scaled); mode 2: fp32 +=
// batch via blockIdx.z: zb=z>>4, zh=z&15; base += zb*sb + zh*sh
template <int BM, int BN, int WR, int WC>
__global__ __launch_bounds__(WR * WC * 64) void gemm_nt(
    const u16* __restrict__ A, int lda, long a_sb, long a_sh,
    const u16* __restrict__ B, int ldb, long b_sb, long b_sh,
    void* __restrict__ C, int ldc, long c_sb, long c_sh,
    int K, float scale, int mode) {
  constexpr int NW = WR * WC;
  constexpr int NTHR = NW * 64;
  constexpr int WTM = BM / WR;
  constexpr int WTN = BN / WC;
  constexpr int MT = WTM / 16;
  constexpr int NT = WTN / 16;
  constexpr int ISA = (BM * 64) / (NTHR * 16);  // 16B slots per thread for A tile
  constexpr int ISB = (BN * 64) / (NTHR * 16);
  static_assert(ISA >= 1 && ISB >= 1, "tile too small");

  __shared__ __align__(16) u16 lA[BM * 32];
  __shared__ __align__(16) u16 lB[BN * 32];

  const int tid = threadIdx.x;
  const int lane = tid & 63;
  const int wave = tid >> 6;
  const int wm = wave / WC;
  const int wn = wave % WC;
  const int m0 = blockIdx.y * BM;
  const int n0 = blockIdx.x * BN;
  const int zb = blockIdx.z >> 4;
  const int zh = blockIdx.z & 15;
  A += (long)zb * a_sb + (long)zh * a_sh;
  B += (long)zb * b_sb + (long)zh * b_sh;
  const long c0 = (long)zb * c_sb + (long)zh * c_sh;

  floatx4 acc[MT][NT];
  for (int mi = 0; mi < MT; mi++)
    for (int ni = 0; ni < NT; ni++)
      for (int r = 0; r < 4; r++) acc[mi][ni][r] = 0.0f;

  const int q_ = lane >> 4;  // 16B chunk wanted by this lane's fragment reads

  for (int k0 = 0; k0 < K; k0 += 32) {
    // stage tiles [BM][32] via async global->LDS; LDS[r][c] = G[r][c ^ ((r>>1)&3)]
    const u16* Ag = A + (long)m0 * lda + k0;
#pragma unroll
    for (int i = 0; i < ISA; i++) {
      int e = (tid + i * NTHR) * 8;   // element offset of this 16B slot (tid-linear)
      int r = e >> 5;
      int c = (e >> 3) & 3;
      int csw = c ^ ((r >> 1) & 3);
      gload_lds16(Ag + (long)r * lda + (csw << 3), &lA[e]);
    }
    const u16* Bg = B + (long)n0 * ldb + k0;
#pragma unroll
    for (int i = 0; i < ISB; i++) {
      int e = (tid + i * NTHR) * 8;
      int r = e >> 5;
      int c = (e >> 3) & 3;
      int csw = c ^ ((r >> 1) & 3);
      gload_lds16(Bg + (long)r * ldb + (csw << 3), &lB[e]);
    }
    __syncthreads();

    bf16x8 af[MT], bfr[NT];
#pragma unroll
    for (int mi = 0; mi < MT; mi++) {
      int r = wm * WTM + mi * 16 + (lane & 15);
      af[mi] = *(const bf16x8*)&lA[(r << 5) + ((q_ ^ ((r >> 1) & 3)) << 3)];
    }
#pragma unroll
    for (int ni = 0; ni < NT; ni++) {
      int r = wn * WTN + ni * 16 + (lane & 15);
      bfr[ni] = *(const bf16x8*)&lB[(r << 5) + ((q_ ^ ((r >> 1) & 3)) << 3)];
    }
#pragma unroll
    for (int mi = 0; mi < MT; mi++)
#pragma unroll
      for (int ni = 0; ni < NT; ni++)
        acc[mi][ni] = __builtin_amdgcn_mfma_f32_16x16x32_bf16(af[mi], bfr[ni], acc[mi][ni], 0, 0, 0);
    __syncthreads();
  }

  // epilogue: D col = lane&15, row = (lane>>4)*4 + reg  [verified m89/m91]
#pragma unroll
  for (int mi = 0; mi < MT; mi++) {
#pragma unroll
    for (int ni = 0; ni < NT; ni++) {
      int col = n0 + wn * WTN + ni * 16 + (lane & 15);
      int rbase = m0 + wm * WTM + mi * 16 + (lane >> 4) * 4;
#pragma unroll
      for (int r = 0; r < 4; r++) {
        float v = acc[mi][ni][r] * scale;
        long idx = c0 + (long)(rbase + r) * ldc + col;
        if (mode == 0)       ((float*)C)[idx] = v;
        else if (mode == 1)  ((u16*)C)[idx] = f2bf(v);
        else                 ((float*)C)[idx] += v;
      }
    }
  }
}

// ---------------- 256x256 deep-pipelined bf16 NT GEMM (8 waves, BK=64) -------------
// T3+T4: raw s_barrier + counted vmcnt (never 0 in steady state); double-buffered
// 128 KiB LDS; T2: chunk XOR-swizzle c ^ (r&7) applied on the global source (LDS
// dest of global_load_lds must be linear) and on ds_read addresses; T5: setprio
// around each 16-MFMA quadrant cluster.
// Schedule per K-tile (4 phases): P1 reads A(mi0-3)+B(ni0-1) frags, MFMA Q00;
// P2 reads B(ni2-3), MFMA Q01; P3 reads A(mi4-7), MFMA Q11, lgkm(0)+barrier
// (all reads of buf[cur] retired); P4 issues tile t+2 staging into buf[cur]
// (8 gload_lds), MFMA Q10, vmcnt(8) (tile t+1 loads landed; t+2 stays in
// flight) + barrier.  MODE 0: fp32 store, MODE 1: bf16 store.
template <int MODE>
__global__ __launch_bounds__(512, 2) void gemm256_nt(
    const u16* __restrict__ A, int lda,
    const u16* __restrict__ B, int ldb,
    void* __restrict__ C, int ldc,
    int K, float scale) {
  __shared__ __align__(16) u16 lA[2][16384];   // [buf][256 rows][8 chunks][8 u16]
  __shared__ __align__(16) u16 lB[2][16384];

  const int tid = threadIdx.x;
  const int lane = tid & 63;
  const int wave = tid >> 6;
  const int wm = wave >> 2;        // 0-1: A-row half
  const int wn = wave & 3;         // 0-3: B-col quarter
  const int m0 = blockIdx.y * 256;
  const int n0 = blockIdx.x * 256;
  const int q = lane >> 4;         // 16B chunk within 32-wide k-slice
  const int rl = lane & 15;

  // lane-constant swizzled chunk byte offsets (u16 units): chunk = (ks*4+q) ^ (row&7),
  // and row&7 == rl&7 for all fragment rows (row = 16-aligned + rl).
  const int ck0 = ((q ^ (rl & 7)) << 3);
  const int ck1 = (((4 | q) ^ (rl & 7)) << 3);
  const int aRow = wm * 128 + rl;  // + mi*16
  const int bRow = wn * 64 + rl;   // + ni*16

  // staging: 4 slots of 16B per thread per tile (256 rows x 8 chunks = 2048 slots)
  int sr[4], sc[4];
#pragma unroll
  for (int i = 0; i < 4; i++) {
    int s = tid + i * 512;
    sr[i] = s >> 3;
    sc[i] = (((s & 7) ^ ((s >> 3) & 7)) << 3);  // source k element offset (swizzled)
  }

#define STAGE256(k0, buf)                                                      \
  {                                                                            \
    _Pragma("unroll")                                                          \
    for (int i = 0; i < 4; i++)                                                \
      gload_lds16(A + (long)(m0 + sr[i]) * lda + (k0) + sc[i],                 \
                  &lA[buf][(tid + i * 512) * 8]);                              \
    _Pragma("unroll")                                                          \
    for (int i = 0; i < 4; i++)                                                \
      gload_lds16(B + (long)(n0 + sr[i]) * ldb + (k0) + sc[i],                 \
                  &lB[buf][(tid + i * 512) * 8]);                              \
  }

  floatx4 acc[8][4];
#pragma unroll
  for (int mi = 0; mi < 8; mi++)
#pragma unroll
    for (int ni = 0; ni < 4; ni++)
#pragma unroll
      for (int r = 0; r < 4; r++) acc[mi][ni][r] = 0.0f;

  const int NKT = K >> 6;
  STAGE256(0, 0);
  if (NKT > 1) {
    STAGE256(64, 1);
    asm volatile("s_waitcnt vmcnt(8)" ::: "memory");
  } else {
    asm volatile("s_waitcnt vmcnt(0)" ::: "memory");
  }
  __builtin_amdgcn_s_barrier();
  __builtin_amdgcn_sched_barrier(0);

  int cur = 0;
  for (int t = 0; t < NKT; t++) {
    const u16* pA = &lA[cur][0];
    const u16* pB = &lB[cur][0];
    bf16x8 aF[4][2], b01[2][2], b23[2][2];

    // ---- P1: A mi0-3 + B ni0-1, MFMA quadrant (mi0-3 x ni0-1) ----
#pragma unroll
    for (int mi = 0; mi < 4; mi++) {
      aF[mi][0] = *(const bf16x8*)&pA[(aRow + mi * 16) * 64 + ck0];
      aF[mi][1] = *(const bf16x8*)&pA[(aRow + mi * 16) * 64 + ck1];
    }
#pragma unroll
    for (int ni = 0; ni < 2; ni++) {
      b01[ni][0] = *(const bf16x8*)&pB[(bRow + ni * 16) * 64 + ck0];
      b01[ni][1] = *(const bf16x8*)&pB[(bRow + ni * 16) * 64 + ck1];
    }
    __builtin_amdgcn_s_setprio(1);
#pragma unroll
    for (int mi = 0; mi < 4; mi++)
#pragma unroll
      for (int ni = 0; ni < 2; ni++) {
        acc[mi][ni] = __builtin_amdgcn_mfma_f32_16x16x32_bf16(aF[mi][0], b01[ni][0], acc[mi][ni], 0, 0, 0);
        acc[mi][ni] = __builtin_amdgcn_mfma_f32_16x16x32_bf16(aF[mi][1], b01[ni][1], acc[mi][ni], 0, 0, 0);
      }
    __builtin_amdgcn_s_setprio(0);

    // ---- P2: B ni2-3, MFMA quadrant (mi0-3 x ni2-3) ----
#pragma unroll
    for (int ni = 0; ni < 2; ni++) {
      b23[ni][0] = *(const bf16x8*)&pB[(bRow + (ni + 2) * 16) * 64 + ck0];
      b23[ni][1] = *(const bf16x8*)&pB[(bRow + (ni + 2) * 16) * 64 + ck1];
    }
    __builtin_amdgcn_s_setprio(1);
#pragma unroll
    for (int mi = 0; mi < 4; mi++)
#pragma unroll
      for (int ni = 0; ni < 2; ni++) {
        acc[mi][ni + 2] = __builtin_amdgcn_mfma_f32_16x16x32_bf16(aF[mi][0], b23[ni][0], acc[mi][ni + 2], 0, 0, 0);
        acc[mi][ni + 2] = __builtin_amdgcn_mfma_f32_16x16x32_bf16(aF[mi][1], b23[ni][1], acc[mi][ni + 2], 0, 0, 0);
      }
    __builtin_amdgcn_s_setprio(0);

    // ---- P3: A mi4-7 (reuse regs), MFMA quadrant (mi4-7 x ni2-3) ----
#pragma unroll
    for (int mi = 0; mi < 4; mi++) {
      aF[mi][0] = *(const bf16x8*)&pA[(aRow + (mi + 4) * 16) * 64 + ck0];
      aF[mi][1] = *(const bf16x8*)&pA[(aRow + (mi + 4) * 16) * 64 + ck1];
    }
    __builtin_amdgcn_s_setprio(1);
#pragma unroll
    for (int mi = 0; mi < 4; mi++)
#pragma unroll
      for (int ni = 0; ni < 2; ni++) {
        acc[mi + 4][ni + 2] = __builtin_amdgcn_mfma_f32_16x16x32_bf16(aF[mi][0], b23[ni][0], acc[mi + 4][ni + 2], 0, 0, 0);
        acc[mi + 4][ni + 2] = __builtin_amdgcn_mfma_f32_16x16x32_bf16(aF[mi][1], b23[ni][1], acc[mi + 4][ni + 2], 0, 0, 0);
      }
    __builtin_amdgcn_s_setprio(0);
    // all ds_reads of buf[cur] must be retired before t+2 staging overwrites it
    asm volatile("s_waitcnt lgkmcnt(0)" ::: "memory");
    __builtin_amdgcn_s_barrier();
    __builtin_amdgcn_sched_barrier(0);

    // ---- P4: issue tile t+2 staging into buf[cur]; MFMA quadrant (mi4-7 x ni0-1) ----
    if (t + 2 < NKT) STAGE256((t + 2) << 6, cur);
    __builtin_amdgcn_s_setprio(1);
#pragma unroll
    for (int mi = 0; mi < 4; mi++)
#pragma unroll
      for (int ni = 0; ni < 2; ni++) {
        acc[mi + 4][ni] = __builtin_amdgcn_mfma_f32_16x16x32_bf16(aF[mi][0], b01[ni][0], acc[mi + 4][ni], 0, 0, 0);
        acc[mi + 4][ni] = __builtin_amdgcn_mfma_f32_16x16x32_bf16(aF[mi][1], b01[ni][1], acc[mi + 4][ni], 0, 0, 0);
      }
    __builtin_amdgcn_s_setprio(0);
    if (t + 1 < NKT) {
      // wait for tile t+1 (issued one iteration ago); leave t+2's 8 loads in flight
      if (t + 2 < NKT) asm volatile("s_waitcnt vmcnt(8)" ::: "memory");
      else             asm volatile("s_waitcnt vmcnt(0)" ::: "memory");
      __builtin_amdgcn_s_barrier();
      __builtin_amdgcn_sched_barrier(0);
    }
    cur ^= 1;
  }
#undef STAGE256

  // epilogue: D col = lane&15, row = (lane>>4)*4 + reg
#pragma unroll
  for (int mi = 0; mi < 8; mi++) {
    int row = m0 + wm * 128 + mi * 16 + q * 4;
#pragma unroll
    for (int ni = 0; ni < 4; ni++) {
      int col = n0 + wn * 64 + ni * 16 + rl;
#pragma unroll
      for (int r = 0; r < 4; r++) {
        float v = acc[mi][ni][r] * scale;
        long idx = (long)(row + r) * ldc + col;
        if (MODE == 0) ((float*)C)[idx] = v;
        else           ((u16*)C)[idx] = f2bf(v);
      }
    }
  }
}

extern "C" void kernel_launch(void* const* d_in, const int* in_sizes, int n_in,
                              void* d_out, int out_size, void* d_ws, size_t ws_size,
                              hipStream_t stream) {
  const int*   tok         = (const int*)d_in[0];
  const int*   pos         = (const int*)d_in[1];
  const float* embed       = (const float*)d_in[2];
  const float* attn_norm_w = (const float*)d_in[3];
  const float* wq          = (const float*)d_in[4];
  const float* wk          = (const float*)d_in[5];
  const float* wv          = (const float*)d_in[6];
  const float* wo          = (const float*)d_in[7];
  const float* ff_norm_w   = (const float*)d_in[8];
  const float* w1          = (const float*)d_in[9];
  const float* w2          = (const float*)d_in[10];
  const float* w3          = (const float*)d_in[11];
  const float* norm_w      = (const float*)d_in[12];

  char* ws = (char*)d_ws;
  u16*   ebf  = (u16*)(ws);                      // 33,554,432 B  (embed bf16)
  u16*   wqkv = (u16*)(ws + 33554432);           //  6,291,456 B
  u16*   wo_b = (u16*)(ws + 39845888);           //  2,097,152 B
  u16*   w13  = (u16*)(ws + 41943040);           // 16,777,216 B
  u16*   w2_b = (u16*)(ws + 58720256);           //  8,388,608 B
  float* x    = (float*)(ws + 67108864);         //  8,388,608 B  (residual, fp32)
  u16*   h    = (u16*)(ws + 75497472);           //  4,194,304 B  (normed, bf16)
  u16*   qkv  = (u16*)(ws + 79691776);           // 12,582,912 B
  u16*   vT   = (u16*)(ws + 92274688);           //  4,194,304 B  [b,h,d,t]
  u16*   o    = (u16*)(ws + 96468992);           //  4,194,304 B
  u16*   S    = (u16*)(ws + 100663296);          // 67,108,864 B  (scores/probs)
  u16*   t13  = S;                               // aliases S (not concurrent)
  u16*   g    = (u16*)(ws + 134217728);          //  8,388,608 B  (aliases S tail)
  // total footprint: 160 MB

  convert_bf16<<<16384, 256, 0, stream>>>(embed, ebf, NVOCAB * DMODEL / 4);
  gather_embed<<<NTOK, 256, 0, stream>>>(tok, embed, x);

  for (int l = 0; l < 4; l++) {
    convert_layer<<<16384, 256, 0, stream>>>(
        wq + (long)l * 1048576, wk + (long)l * 1048576, wv + (long)l * 1048576,
        wo + (long)l * 1048576, w1 + (long)l * 4194304, w3 + (long)l * 4194304,
        w2 + (long)l * 4194304, wqkv, wo_b, w13, w2_b);

    // attention
    rmsnorm_bf16<<<NTOK, 256, 0, stream>>>(x, attn_norm_w + l * 1024, h);
    gemm_nt<128, 128, 2, 2><<<dim3(24, 16, 1), 256, 0, stream>>>(
        h, 1024, 0, 0, wqkv, 1024, 0, 0, qkv, 3072, 0, 0, 1024, 1.0f, 1);
    rope_qk<<<NTOK, 256, 0, stream>>>(qkv, pos);
    transpose_v<<<dim3(16, 32), 256, 0, stream>>>(qkv, vT);
    // S[z][t][s] = (q . k) * 1/8,  z = b*16+h
    gemm_nt<128, 128, 2, 2><<<dim3(8, 8, 32), 256, 0, stream>>>(
        qkv, 3072, 3145728L, 64L,
        qkv + 1024, 3072, 3145728L, 64L,
        S, 1024, 16777216L, 1048576L, 64, 0.125f, 1);
    softmax_rows<<<32768, 256, 0, stream>>>(S);
    // O[z][t][d] = P . vT   (64x64 tile -> 512 blocks = 2/CU)
    gemm_nt<64, 64, 2, 2><<<dim3(1, 16, 32), 256, 0, stream>>>(
        S, 1024, 16777216L, 1048576L,
        vT, 1024, 1048576L, 65536L,
        o, 1024, 1048576L, 64L, 1024, 1.0f, 1);
    // x += O @ wo^T
    gemm_nt<64, 128, 2, 2><<<dim3(8, 32, 1), 256, 0, stream>>>(
        o, 1024, 0, 0, wo_b, 1024, 0, 0, x, 1024, 0, 0, 1024, 1.0f, 2);

    // FFN
    rmsnorm_bf16<<<NTOK, 256, 0, stream>>>(x, ff_norm_w + l * 1024, h);
    // t13 = h @ w13^T  (256^2 deep-pipelined)
    gemm256_nt<1><<<dim3(32, 8, 1), 512, 0, stream>>>(
        h, 1024, w13, 1024, t13, 8192, 1024, 1.0f);
    swiglu<<<4096, 256, 0, stream>>>(t13, g);
    gemm_nt<64, 128, 2, 2><<<dim3(8, 32, 1), 256, 0, stream>>>(
        g, 4096, 0, 0, w2_b, 4096, 0, 0, x, 1024, 0, 0, 4096, 1.0f, 2);
  }

  rmsnorm_bf16<<<NTOK, 256, 0, stream>>>(x, norm_w, h);
  // logits = xn @ embed^T  -> d_out fp32 [2048, 16384]  (256^2 deep-pipelined)
  gemm256_nt<0><<<dim3(64, 8, 1), 512, 0, stream>>>(
      h, 1024, ebf, 1024, d_out, 16384, 1024, 1.0f);
}